// Round 4
// baseline (6635.728 us; speedup 1.0000x reference)
//
#include <hip/hip_runtime.h>

// ---------------------------------------------------------------------------
// Teacher_model_7464653160858: embed+BN -> 3x GRU(1024, reset_after) -> dense+softmax
// B=64, T=512, E=256, U=1024, V=512.
//
// R7: FIRE-AND-FORGET PUBLISH + CSUM VALIDATION. R6 post-mortem: FETCH=346MB
// proves slab reads are L2-shared per XCD (one MALL fill, 32 WGs hit) -> the
// 7.76us period is the serial spine: gate -> drain(vmcnt0 at __syncthreads)
// -> flag -> detect -> read -> compute. This round removes the drain links:
//  - Producer: pk stores + per-chunk XOR csum (masked with (s+1)*GOLDEN) +
//    flag, ALL fire-and-forget. Barriers are RAW s_barrier (lgkmcnt only for
//    LDS) -- no vmcnt(0) drain anywhere in the step loop.
//  - Consumer: flag detect as R6 (flag now ~2us earlier), PLAIN cached reads
//    (keeps the 32-WG L2 sharing), then validates each 16B chunk vs csum^M.
//    Mismatch (chunk in flight / stale L2 line from ring reuse) -> rare
//    retry with sc0sc1 bypass loads. Validation subsumes ALL staleness ->
//    no epoch fences needed; ring R=128.
//  - Back-pressure via flags every 16 steps with 16-step margin (amortizes
//    the vmcnt(0) that atomic flag loads imply).
//  - Everything else from R6 kept: 8-wave WGs, per-wave dependency polls,
//    register weights, XCD-pair placement, reduce/gating layout.
// ---------------------------------------------------------------------------

typedef short bf16x8 __attribute__((ext_vector_type(8)));
typedef float f32x4 __attribute__((ext_vector_type(4)));
typedef float f32x2 __attribute__((ext_vector_type(2)));
typedef unsigned u32x4 __attribute__((ext_vector_type(4)));
typedef unsigned short ushort_t;

#define MFMA16(a, b, c) __builtin_amdgcn_mfma_f32_16x16x32_bf16((a), (b), (c), 0, 0, 0)

#define SLAB 65536        // elems per h slab: 128 u8-groups * 64 b * 8 (128 KB)
#define RING 128          // slabs per layer ring
#define CSLAB 8192        // csum dwords per slab: 128 u8-groups * 64 b
#define EPOCH_MUL 0x9E3779B9u

// bypass loads (L1+L2) for retry-refresh; rare path only.
#define LD16(dst, p) asm volatile("global_load_dwordx4 %0, %1, off sc0 sc1" \
                                  : "=v"(dst) : "v"(p) : "memory")
#define LD4(dst, p)  asm volatile("global_load_dword %0, %1, off sc0 sc1"   \
                                  : "=v"(dst) : "v"(p) : "memory")
#define WAITV0 { asm volatile("s_waitcnt vmcnt(0)" ::: "memory"); \
                 __builtin_amdgcn_sched_barrier(0); }
#define XR4(v) ((v)[0] ^ (v)[1] ^ (v)[2] ^ (v)[3])

__device__ __forceinline__ float bf2f(ushort_t h) {
    return __uint_as_float(((unsigned)h) << 16);
}
__device__ __forceinline__ ushort_t f2bf(float f) {
    unsigned u = __float_as_uint(f);
    u += 0x7FFFu + ((u >> 16) & 1u);   // RNE
    return (ushort_t)(u >> 16);
}
__device__ __forceinline__ float sigmf(float x) { return 1.f / (1.f + __expf(-x)); }
__device__ __forceinline__ float tanhfast(float x) {
    float e = __expf(2.f * x);
    return 1.f - 2.f / (e + 1.f);
}

// ---------------------------------------------------------------------------
// pack: W[K][3072] fp32 -> WT[3072][K] bf16 (transpose). grid (K/64, 48).
// ---------------------------------------------------------------------------
__global__ __launch_bounds__(256, 1) void pack_w(
    const float* __restrict__ W, ushort_t* __restrict__ WT, int K)
{
    __shared__ ushort_t tile[64][72];
    const int kt0 = blockIdx.x * 64;
    const int ct0 = blockIdx.y * 64;
    const int tx = threadIdx.x & 63;
    const int ty = threadIdx.x >> 6;
#pragma unroll
    for (int i = 0; i < 16; ++i) {
        int k = kt0 + ty * 16 + i;
        tile[ty * 16 + i][tx] = f2bf(W[(size_t)k * 3072 + ct0 + tx]);
    }
    __syncthreads();
#pragma unroll
    for (int i = 0; i < 16; ++i) {
        int c = ct0 + ty * 16 + i;
        WT[(size_t)c * K + kt0 + tx] = tile[tx][ty * 16 + i];
    }
}

// ---------------------------------------------------------------------------
// BN-folded embedding table (512x256 bf16)
// ---------------------------------------------------------------------------
__global__ __launch_bounds__(256, 1) void embed_bn(
    const float* __restrict__ emb,
    const float* __restrict__ gamma, const float* __restrict__ beta,
    const float* __restrict__ mean, const float* __restrict__ var,
    ushort_t* __restrict__ embBN)
{
    const int idx = blockIdx.x * 256 + threadIdx.x;
    const int e = idx & 255;
    const float sc = gamma[e] * rsqrtf(var[e] + 1e-3f);
    const float sh = beta[e] - mean[e] * sc;
    embBN[idx] = f2bf(fmaf(emb[idx], sc, sh));
}

// ---------------------------------------------------------------------------
// gru_run: one GRU layer, 64 WGs x 512 thr (8 waves), 512 steps.
//   XKC=8  (L0): w0 = x (embBN gather); w1..w7 = h {5,5,5,5,4,4,4} kc
//   XKC=32 (L1/2): w0..w3 = x (prev slab); w4..w7 = h (own slab)
// ---------------------------------------------------------------------------
template<int XKC, bool EMB>
__device__ __forceinline__ void gru_run(
    const int* __restrict__ tokens,
    const ushort_t* __restrict__ embBN,
    const ushort_t* __restrict__ WkT,      // [3072][XKC*32]
    const ushort_t* __restrict__ WrT,      // [3072][1024]
    const float* __restrict__ gb,          // [2][3072] flat
    ushort_t* __restrict__ hxOwn,          // own slab ring base
    const ushort_t* __restrict__ hxPrev,   // prev-layer slab ring (null if EMB)
    unsigned* __restrict__ csOwn,          // own csum ring base
    const unsigned* __restrict__ csPrev,   // prev-layer csum ring
    float* __restrict__ Hf,                // non-null on last layer only
    unsigned* __restrict__ flags,          // [3*64]
    const int layer, const int lwg,
    f32x4* __restrict__ ldsRed)            // [8][4][3][64]
{
    const int tid  = threadIdx.x;
    const int lane = tid & 63;
    const int w    = tid >> 6;             // 0..7
    const int n    = lane & 15, quad = lane >> 4;
    const int u_   = lwg * 16 + n;

    bool ISX; int CNT, BASE;
    if (XKC == 8) {
        ISX = (w == 0);
        if (w == 0)      { CNT = 8; BASE = 0; }
        else if (w <= 4) { CNT = 5; BASE = (w - 1) * 5; }
        else             { CNT = 4; BASE = 20 + (w - 5) * 4; }
    } else {
        ISX = (w < 4);
        CNT = 8; BASE = (w & 3) * 8;
    }
    const int KROW = ISX ? (EMB ? 256 : 1024) : 1024;
    const ushort_t* WT = ISX ? WkT : WrT;

    // once per dispatch: drop stale/poisoned L2 lines from prior launches
    __threadfence();

    // ---- preload weight B-fragments to registers (static-indexed) ----
    bf16x8 wf[8][3];
#pragma unroll
    for (int i = 0; i < 8; ++i)
        if (i < CNT) {
            const int kc = BASE + i;
#pragma unroll
            for (int g = 0; g < 3; ++g)
                wf[i][g] = *(const bf16x8*)(WT + (size_t)(g * 1024 + u_) * KROW
                                            + kc * 32 + quad * 8);
        }

    const float bzz = gb[u_]        + gb[3072 + u_];
    const float brr = gb[1024 + u_] + gb[4096 + u_];
    const float bxh = gb[2048 + u_];
    const float brh = gb[5120 + u_];

    const int g16  = lane >> 4;
    const int myrt = w >> 1;
    const int q    = (w & 1) * 2 + (g16 >> 1);
    const int reg0 = (g16 & 1) * 2;
    const int r0   = w * 8 + g16 * 2;
    const int off  = q * 16 + n;
    float hcur0 = 0.f, hcur1 = 0.f;

    for (int s = 0; s < 512; ++s) {
        // ---- 0. strided back-pressure (all waves, every 16 steps, 16 margin)
        if (layer < 2 && (s & 15) == 0 && s + 16 > RING) {
            const unsigned tgt = (unsigned)(s + 16 - RING);
            const unsigned* fN = flags + (layer + 1) * 64 + lane;
            while (__ballot(__hip_atomic_load(fN, __ATOMIC_RELAXED,
                     __HIP_MEMORY_SCOPE_AGENT) >= tgt) != ~0ull)
                __builtin_amdgcn_s_sleep(1);
        }

        // ---- 1. per-wave dependency detect (flag = "stores issued")
        if (!ISX) {
            if (s > 0) {
                const unsigned ownT = (unsigned)s;
                const unsigned* fO = flags + layer * 64 + lane;
                while (__ballot(__hip_atomic_load(fO, __ATOMIC_RELAXED,
                         __HIP_MEMORY_SCOPE_AGENT) >= ownT) != ~0ull)
                    __builtin_amdgcn_s_sleep(1);
            }
        } else if (!EMB) {
            const unsigned prvT = (unsigned)(s + 1);
            const unsigned* fP = flags + (layer - 1) * 64 + lane;
            while (__ballot(__hip_atomic_load(fP, __ATOMIC_RELAXED,
                     __HIP_MEMORY_SCOPE_AGENT) >= prvT) != ~0ull)
                __builtin_amdgcn_s_sleep(1);
        }
        asm volatile("" ::: "memory");        // no load hoisting above the poll

        // ---- 2. MFMA: plain cached loads + csum validation (+rare bypass retry)
        f32x4 acc[4][3] = {};
        if (ISX && EMB) {
            int tk[4];
#pragma unroll
            for (int rt = 0; rt < 4; ++rt)
                tk[rt] = tokens[(rt * 16 + n) * 512 + s] * 256;
#pragma unroll
            for (int i = 0; i < 8; ++i)
                if (i < CNT) {
                    const int kc = BASE + i;
                    bf16x8 a[4];
#pragma unroll
                    for (int rt = 0; rt < 4; ++rt)
                        a[rt] = *(const bf16x8*)(embBN + (size_t)tk[rt]
                                                 + kc * 32 + quad * 8);
#pragma unroll
                    for (int rt = 0; rt < 4; ++rt)
#pragma unroll
                        for (int g = 0; g < 3; ++g)
                            acc[rt][g] = MFMA16(a[rt], wf[i][g], acc[rt][g]);
                }
        } else if (ISX || s > 0) {
            const int epoch = ISX ? s : (s - 1);
            const unsigned M = (unsigned)(epoch + 1) * EPOCH_MUL;
            const ushort_t* slab = (ISX ? hxPrev : hxOwn)
                                   + (size_t)(epoch & (RING - 1)) * SLAB;
            const unsigned* csb  = (ISX ? csPrev : csOwn)
                                   + (size_t)(epoch & (RING - 1)) * CSLAB;
#pragma unroll
            for (int i = 0; i < 8; ++i)
                if (i < CNT) {
                    const int kc = BASE + i;
                    const ushort_t* sp = slab + (size_t)(kc * 4 + quad) * 512 + n * 8;
                    const unsigned* cb = csb + (size_t)(kc * 4 + quad) * 64 + n;
                    u32x4 av0 = *(const u32x4*)(sp);
                    u32x4 av1 = *(const u32x4*)(sp + 128);
                    u32x4 av2 = *(const u32x4*)(sp + 256);
                    u32x4 av3 = *(const u32x4*)(sp + 384);
                    unsigned c0 = cb[0], c1 = cb[16], c2 = cb[32], c3 = cb[48];
                    int ok = (XR4(av0) == (c0 ^ M)) & (XR4(av1) == (c1 ^ M)) &
                             (XR4(av2) == (c2 ^ M)) & (XR4(av3) == (c3 ^ M));
                    while (!__all(ok)) {
                        LD16(av0, sp);       LD16(av1, sp + 128);
                        LD16(av2, sp + 256); LD16(av3, sp + 384);
                        LD4(c0, cb);         LD4(c1, cb + 16);
                        LD4(c2, cb + 32);    LD4(c3, cb + 48);
                        WAITV0;
                        ok = (XR4(av0) == (c0 ^ M)) & (XR4(av1) == (c1 ^ M)) &
                             (XR4(av2) == (c2 ^ M)) & (XR4(av3) == (c3 ^ M));
                        if (!ok) __builtin_amdgcn_s_sleep(1);
                    }
#pragma unroll
                    for (int g = 0; g < 3; ++g) {
                        acc[0][g] = MFMA16(__builtin_bit_cast(bf16x8, av0), wf[i][g], acc[0][g]);
                        acc[1][g] = MFMA16(__builtin_bit_cast(bf16x8, av1), wf[i][g], acc[1][g]);
                        acc[2][g] = MFMA16(__builtin_bit_cast(bf16x8, av2), wf[i][g], acc[2][g]);
                        acc[3][g] = MFMA16(__builtin_bit_cast(bf16x8, av3), wf[i][g], acc[3][g]);
                    }
                }
        }

        // ---- 3. cross-wave K-reduce staging
#pragma unroll
        for (int rt = 0; rt < 4; ++rt)
#pragma unroll
            for (int g = 0; g < 3; ++g)
                ldsRed[((w * 4 + rt) * 3 + g) * 64 + lane] = acc[rt][g];
        // B1: RAW barrier -- LDS drain only, NO vmcnt drain
        asm volatile("s_waitcnt lgkmcnt(0)" ::: "memory");
        __builtin_amdgcn_s_barrier();
        __builtin_amdgcn_sched_barrier(0);

        // ---- 4. reduce + gate rows r0, r0+1 (all 8 waves)
        const float* ldsF = (const float*)ldsRed;
        float sz0 = 0.f, sz1 = 0.f, sr0 = 0.f, sr1 = 0.f;
        float sxh0 = 0.f, sxh1 = 0.f, srh0 = 0.f, srh1 = 0.f;
#pragma unroll
        for (int wp = 0; wp < 8; ++wp) {
            const bool xw = (XKC == 8) ? (wp == 0) : (wp < 4);
            const int tb = (wp * 4 + myrt) * 3;
            f32x2 vz = *(const f32x2*)(ldsF + ((size_t)(tb + 0) * 64 + off) * 4 + reg0);
            f32x2 vr = *(const f32x2*)(ldsF + ((size_t)(tb + 1) * 64 + off) * 4 + reg0);
            f32x2 vh = *(const f32x2*)(ldsF + ((size_t)(tb + 2) * 64 + off) * 4 + reg0);
            sz0 += vz[0]; sz1 += vz[1];
            sr0 += vr[0]; sr1 += vr[1];
            if (xw) { sxh0 += vh[0]; sxh1 += vh[1]; }
            else    { srh0 += vh[0]; srh1 += vh[1]; }
        }
        float hn0, hn1;
        {
            const float z  = sigmf(sz0 + bzz);
            const float r  = sigmf(sr0 + brr);
            const float hh = tanhfast(sxh0 + bxh + r * (srh0 + brh));
            hn0 = z * hcur0 + (1.f - z) * hh; hcur0 = hn0;
        }
        {
            const float z  = sigmf(sz1 + bzz);
            const float r  = sigmf(sr1 + brr);
            const float hh = tanhfast(sxh1 + bxh + r * (srh1 + brh));
            hn1 = z * hcur1 + (1.f - z) * hh; hcur1 = hn1;
        }

        // ---- 5. publish h_s + csums + flag: ALL fire-and-forget (no drain)
        {
            ushort_t* sw = hxOwn + (size_t)(s & (RING - 1)) * SLAB;
            unsigned* cw = csOwn + (size_t)(s & (RING - 1)) * CSLAB;
            const unsigned Mw = (unsigned)(s + 1) * EPOCH_MUL;
            const float p0 = __shfl_xor(hn0, 1);
            const float p1 = __shfl_xor(hn1, 1);
            if ((lane & 1) == 0) {
                const unsigned pk0 = (unsigned)f2bf(hn0) | ((unsigned)f2bf(p0) << 16);
                const unsigned pk1 = (unsigned)f2bf(hn1) | ((unsigned)f2bf(p1) << 16);
                const size_t e0 = ((size_t)(u_ >> 3) * 64 + r0) * 8 + (u_ & 7);
                const size_t e1 = ((size_t)(u_ >> 3) * 64 + r0 + 1) * 8 + (u_ & 7);
                __hip_atomic_store((unsigned*)sw + (e0 >> 1), pk0,
                                   __ATOMIC_RELAXED, __HIP_MEMORY_SCOPE_AGENT);
                __hip_atomic_store((unsigned*)sw + (e1 >> 1), pk1,
                                   __ATOMIC_RELAXED, __HIP_MEMORY_SCOPE_AGENT);
                // csum over the 4 dwords of each 16B chunk (lanes n, n+2, n+4, n+6)
                unsigned c0 = pk0 ^ __shfl_xor(pk0, 2);
                c0 ^= __shfl_xor(c0, 4);
                unsigned c1 = pk1 ^ __shfl_xor(pk1, 2);
                c1 ^= __shfl_xor(c1, 4);
                if ((lane & 7) == 0) {
                    const int G = u_ >> 3;
                    __hip_atomic_store(cw + G * 64 + r0,     c0 ^ Mw,
                                       __ATOMIC_RELAXED, __HIP_MEMORY_SCOPE_AGENT);
                    __hip_atomic_store(cw + G * 64 + r0 + 1, c1 ^ Mw,
                                       __ATOMIC_RELAXED, __HIP_MEMORY_SCOPE_AGENT);
                }
            }
        }
        if (tid == 0)
            __hip_atomic_store(flags + layer * 64 + lwg, (unsigned)(s + 1),
                               __ATOMIC_RELAXED, __HIP_MEMORY_SCOPE_AGENT);

        // B2: RAW barrier (protects ldsRed reuse), NO vmcnt drain
        __builtin_amdgcn_s_barrier();
        __builtin_amdgcn_sched_barrier(0);
    }

    if (Hf != nullptr) {
        Hf[(size_t)r0 * 1024 + u_]       = hcur0;
        Hf[(size_t)(r0 + 1) * 1024 + u_] = hcur1;
    }
}

// ---------------------------------------------------------------------------
// fused 3-layer pipelined GRU. grid = 256 WGs x 512 thr; XCD slot mapping:
// slots {0,1}->L0, {2,3}->L1, {4,5}->L2, {6,7} exit. lwg = rep*2+(slot&1).
// ---------------------------------------------------------------------------
__global__ __launch_bounds__(512, 2) void gru_fused(
    const int* __restrict__ tokens, const ushort_t* __restrict__ embBN,
    const ushort_t* __restrict__ WkT0, const ushort_t* __restrict__ WkT1,
    const ushort_t* __restrict__ WkT2,
    const ushort_t* __restrict__ WrT0, const ushort_t* __restrict__ WrT1,
    const ushort_t* __restrict__ WrT2,
    const float* __restrict__ gb0, const float* __restrict__ gb1,
    const float* __restrict__ gb2,
    ushort_t* __restrict__ Hx, unsigned* __restrict__ Cs,
    float* __restrict__ Hf, unsigned* __restrict__ flags)
{
    __shared__ f32x4 ldsRed[6144];            // 96 KB: 8 waves x 4 rt x 3 g x 64
    const int slot = blockIdx.x & 7;
    const int rep  = blockIdx.x >> 3;         // 0..31
    const int layer = slot >> 1;
    if (layer >= 3) return;                   // slots 6,7: idle
    const int lwg = rep * 2 + (slot & 1);     // 0..63
    ushort_t* hxL = Hx + (size_t)layer * RING * SLAB;
    unsigned* csL = Cs + (size_t)layer * RING * CSLAB;
    const ushort_t* hxP = (layer > 0) ? (Hx + (size_t)(layer - 1) * RING * SLAB) : nullptr;
    const unsigned* csP = (layer > 0) ? (Cs + (size_t)(layer - 1) * RING * CSLAB) : nullptr;

    if (layer == 0)
        gru_run<8,  true >(tokens, embBN, WkT0, WrT0, gb0, hxL, nullptr, csL, nullptr,
                           nullptr, flags, 0, lwg, ldsRed);
    else if (layer == 1)
        gru_run<32, false>(nullptr, nullptr, WkT1, WrT1, gb1, hxL, hxP, csL, csP,
                           nullptr, flags, 1, lwg, ldsRed);
    else
        gru_run<32, false>(nullptr, nullptr, WkT2, WrT2, gb2, hxL, hxP, csL, csP,
                           Hf, flags, 2, lwg, ldsRed);
}

// ---------------------------------------------------------------------------
// dense + softmax (verified). One WG per (b,f).
// ---------------------------------------------------------------------------
__global__ __launch_bounds__(256, 1) void dense_softmax(
    const float* __restrict__ hfinal, const float* __restrict__ Wd,
    const float* __restrict__ bd, float* __restrict__ out)
{
    const int tid = threadIdx.x;
    const int bf = blockIdx.x;
    __shared__ float sv[256];
    __shared__ float red[256];
    sv[tid] = hfinal[bf * 256 + tid];
    __syncthreads();
    float a0 = bd[tid], a1 = bd[tid + 256];
    for (int d = 0; d < 256; ++d) {
        float s = sv[d];
        a0 = fmaf(s, Wd[d * 512 + tid], a0);
        a1 = fmaf(s, Wd[d * 512 + tid + 256], a1);
    }
    red[tid] = fmaxf(a0, a1);
    __syncthreads();
    for (int st = 128; st > 0; st >>= 1) {
        if (tid < st) red[tid] = fmaxf(red[tid], red[tid + st]);
        __syncthreads();
    }
    const float mx = red[0];
    __syncthreads();
    float e0 = __expf(a0 - mx), e1 = __expf(a1 - mx);
    red[tid] = e0 + e1;
    __syncthreads();
    for (int st = 128; st > 0; st >>= 1) {
        if (tid < st) red[tid] += red[tid + st];
        __syncthreads();
    }
    const float inv = 1.f / red[0];
    out[(size_t)bf * 512 + tid] = e0 * inv;
    out[(size_t)bf * 512 + tid + 256] = e1 * inv;
}

// ---------------------------------------------------------------------------
extern "C" void kernel_launch(void* const* d_in, const int* in_sizes, int n_in,
                              void* d_out, int out_size, void* d_ws, size_t ws_size,
                              hipStream_t stream)
{
    (void)in_sizes; (void)n_in; (void)out_size; (void)ws_size;

    const int*   tokens = (const int*)d_in[0];
    const float* emb    = (const float*)d_in[1];
    const float* gamma  = (const float*)d_in[2];
    const float* beta   = (const float*)d_in[3];
    const float* mean   = (const float*)d_in[4];
    const float* var    = (const float*)d_in[5];
    const float* gk[3]  = {(const float*)d_in[6], (const float*)d_in[9],  (const float*)d_in[12]};
    const float* gr[3]  = {(const float*)d_in[7], (const float*)d_in[10], (const float*)d_in[13]};
    const float* gbb[3] = {(const float*)d_in[8], (const float*)d_in[11], (const float*)d_in[14]};
    const float* dw  = (const float*)d_in[15];
    const float* db  = (const float*)d_in[16];

    // workspace carve: fixed ~33.6 MB + Hx 48 MB + Cs 12 MB ~= 94 MB
    char* p = (char*)d_ws;
    ushort_t* WkT0  = (ushort_t*)p; p += (size_t)3072 * 256 * 2;
    ushort_t* WkT1  = (ushort_t*)p; p += (size_t)3072 * 1024 * 2;
    ushort_t* WkT2  = (ushort_t*)p; p += (size_t)3072 * 1024 * 2;
    ushort_t* WrTb[3];
    for (int l = 0; l < 3; ++l) { WrTb[l] = (ushort_t*)p; p += (size_t)3072 * 1024 * 2; }
    ushort_t* embBN = (ushort_t*)p; p += (size_t)512 * 256 * 2;
    float*    Hf    = (float*)p;    p += (size_t)64 * 1024 * 4;
    unsigned* flags = (unsigned*)p; p += 4096;
    ushort_t* Hx    = (ushort_t*)p; p += (size_t)3 * RING * SLAB * 2;
    unsigned* Cs    = (unsigned*)p; p += (size_t)3 * RING * CSLAB * 4;

    // MUST zero every launch: 0xAA ws poison would satisfy every flag poll.
    // (Slab/csum rings need NO zeroing: poisoned csum never matches epoch mask.)
    hipMemsetAsync(flags, 0, 4096, stream);

    pack_w<<<dim3(4, 48),  256, 0, stream>>>(gk[0], WkT0, 256);
    pack_w<<<dim3(16, 48), 256, 0, stream>>>(gk[1], WkT1, 1024);
    pack_w<<<dim3(16, 48), 256, 0, stream>>>(gk[2], WkT2, 1024);
    for (int l = 0; l < 3; ++l)
        pack_w<<<dim3(16, 48), 256, 0, stream>>>(gr[l], WrTb[l], 1024);

    embed_bn<<<512, 256, 0, stream>>>(emb, gamma, beta, mean, var, embBN);

    gru_fused<<<256, 512, 0, stream>>>(
        tokens, embBN, WkT0, WkT1, WkT2,
        WrTb[0], WrTb[1], WrTb[2], gbb[0], gbb[1], gbb[2],
        Hx, Cs, Hf, flags);

    dense_softmax<<<256, 256, 0, stream>>>(Hf, dw, db, (float*)d_out);
}

// Round 6
// 3537.495 us; speedup vs baseline: 1.8758x; 1.8758x over previous
//
#include <hip/hip_runtime.h>

// ---------------------------------------------------------------------------
// Teacher_model_7464653160858: embed+BN -> 3x GRU(1024, reset_after) -> dense+softmax
// B=64, T=512, E=256, U=1024, V=512.
//
// R9: TWO-PHASE BATCH INTERLEAVE on the verified R6 protocol. R8 post-mortem:
// same-XCD plain-store exchange deadlocked (correctness depended on WG->XCD
// mapping -- Guideline 16). R9 keeps ALL exchange device-scope (MALL) and
// instead hides the MALL ordering latency: batch rows are independent
// recurrence chains, so the 64-row step splits into two 32-row halves
// processed alternately in the same WGs.
//  - Phase P(s): poll (pre-satisfied) -> loads+MFMA acc[2][3] -> stage ->
//    __syncthreads (drains PREV phase's stores at zero cost: this phase's
//    loads are waited on anyway) -> tid0 publishes PREV phase's flag
//    (deferred ack) -> reduce+gate -> fire-and-forget publish.
//  - ldsRed double-buffered by phase (2x48KB): ONE barrier per phase
//    (write of buf[P] at step s+1 is separated from reads at step s by the
//    intervening other-phase barrier). 2 barriers/step, same as R6.
//  - Store-drain and flag MALL-visibility now overlap the other half's
//    compute -> they leave the serial spine.
//  - Kept verified: monotonic flags memset each launch, relaxed agent
//    atomics, lane-parallel ballot polls, XCD-pair placement as PERF HINT
//    ONLY (slots {0,1}->L0 {2,3}->L1 {4,5}->L2, {6,7} exit), register
//    weights, adaptive ring (512 no-reuse / 256 + threadfence at s==256),
//    strided back-pressure (margin 16), post-loop final flag publish.
// ---------------------------------------------------------------------------

typedef short bf16x8 __attribute__((ext_vector_type(8)));
typedef float f32x4 __attribute__((ext_vector_type(4)));
typedef unsigned short ushort_t;

#define MFMA16(a, b, c) __builtin_amdgcn_mfma_f32_16x16x32_bf16((a), (b), (c), 0, 0, 0)

#define SLAB_H 32768      // half-slab elems: 128 u8-groups * 32 rows * 8 (64 KB)

__device__ __forceinline__ float bf2f(ushort_t h) {
    return __uint_as_float(((unsigned)h) << 16);
}
__device__ __forceinline__ ushort_t f2bf(float f) {
    unsigned u = __float_as_uint(f);
    u += 0x7FFFu + ((u >> 16) & 1u);   // RNE
    return (ushort_t)(u >> 16);
}
__device__ __forceinline__ float sigmf(float x) { return 1.f / (1.f + __expf(-x)); }
__device__ __forceinline__ float tanhfast(float x) {
    float e = __expf(2.f * x);
    return 1.f - 2.f / (e + 1.f);
}

// lane-parallel poll: wait until all 64 flags at base[0..63] >= tgt
__device__ __forceinline__ void poll_ge(const unsigned* base, unsigned tgt) {
    const unsigned* p = base + (threadIdx.x & 63);
    while (true) {
        unsigned v = __hip_atomic_load(p, __ATOMIC_RELAXED, __HIP_MEMORY_SCOPE_AGENT);
        if (__ballot(v >= tgt) == ~0ull) break;
        __builtin_amdgcn_s_sleep(1);
    }
}

// ---------------------------------------------------------------------------
// pack: W[K][3072] fp32 -> WT[3072][K] bf16 (transpose). grid (K/64, 48).
// ---------------------------------------------------------------------------
__global__ __launch_bounds__(256, 1) void pack_w(
    const float* __restrict__ W, ushort_t* __restrict__ WT, int K)
{
    __shared__ ushort_t tile[64][72];
    const int kt0 = blockIdx.x * 64;
    const int ct0 = blockIdx.y * 64;
    const int tx = threadIdx.x & 63;
    const int ty = threadIdx.x >> 6;
#pragma unroll
    for (int i = 0; i < 16; ++i) {
        int k = kt0 + ty * 16 + i;
        tile[ty * 16 + i][tx] = f2bf(W[(size_t)k * 3072 + ct0 + tx]);
    }
    __syncthreads();
#pragma unroll
    for (int i = 0; i < 16; ++i) {
        int c = ct0 + ty * 16 + i;
        WT[(size_t)c * K + kt0 + tx] = tile[tx][ty * 16 + i];
    }
}

// ---------------------------------------------------------------------------
// BN-folded embedding table (512x256 bf16)
// ---------------------------------------------------------------------------
__global__ __launch_bounds__(256, 1) void embed_bn(
    const float* __restrict__ emb,
    const float* __restrict__ gamma, const float* __restrict__ beta,
    const float* __restrict__ mean, const float* __restrict__ var,
    ushort_t* __restrict__ embBN)
{
    const int idx = blockIdx.x * 256 + threadIdx.x;
    const int e = idx & 255;
    const float sc = gamma[e] * rsqrtf(var[e] + 1e-3f);
    const float sh = beta[e] - mean[e] * sc;
    embBN[idx] = f2bf(fmaf(emb[idx], sc, sh));
}

// ---------------------------------------------------------------------------
// one half-batch phase. Uniform across the WG (all waves reach the barrier).
// ---------------------------------------------------------------------------
template<int XKC, bool EMB>
__device__ __forceinline__ void gru_phase(
    const int s, const int tid, const int lane, const int w,
    const int n, const int quad,
    const bool ISX, const int CNT, const int BASE,
    const int phRow,                       // 0 or 32 (token row offset)
    const int mask,                        // RING-1
    const int* __restrict__ tokens, const ushort_t* __restrict__ embBN,
    const ushort_t* __restrict__ rdPrv,    // prev-layer ring base, this half
    const ushort_t* __restrict__ rdOwn,    // own ring base, this half
    ushort_t* __restrict__ wrOwn,          // own ring base, this half
    const unsigned* pollPrv,               // prev flags base (this half) / null
    const unsigned* pollOwn,               // own flags base (this half) / null
    unsigned* pubPtr, const unsigned pubVal,   // deferred flag (tid0) / null
    const unsigned* bpPtr, const unsigned bpTgt,
    const bf16x8 (&wf)[8][3],
    const float bzz, const float brr, const float bxh, const float brh,
    const int rt_src, const int quad_src, const int reg,
    const int r_local, const int u_,
    float& hc, f32x4* __restrict__ ldsPh)
{
    // ---- 0. strided back-pressure (all waves)
    if (bpPtr) poll_ge(bpPtr, bpTgt);

    // ---- 1. per-wave dependency polls
    if (!ISX) {
        if (pollOwn) poll_ge(pollOwn, (unsigned)s);
    } else if (!EMB) {
        poll_ge(pollPrv, (unsigned)(s + 1));
    }
    asm volatile("" ::: "memory");         // no load hoisting above the poll

    // ---- 2. MFMA: this wave's K-slice (weights in regs, A from slabs)
    f32x4 acc[2][3] = {};
    if (ISX && EMB) {
        int tk[2];
#pragma unroll
        for (int rt = 0; rt < 2; ++rt)
            tk[rt] = tokens[(phRow + rt * 16 + n) * 512 + s] * 256;
#pragma unroll
        for (int i = 0; i < 8; ++i)
            if (i < CNT) {
                const int kc = BASE + i;
                bf16x8 a[2];
#pragma unroll
                for (int rt = 0; rt < 2; ++rt)
                    a[rt] = *(const bf16x8*)(embBN + (size_t)tk[rt] + kc * 32 + quad * 8);
#pragma unroll
                for (int rt = 0; rt < 2; ++rt)
#pragma unroll
                    for (int g = 0; g < 3; ++g)
                        acc[rt][g] = MFMA16(a[rt], wf[i][g], acc[rt][g]);
            }
    } else if (ISX) {
        const ushort_t* slab = rdPrv + (size_t)(s & mask) * SLAB_H;
#pragma unroll
        for (int i = 0; i < 8; ++i)
            if (i < CNT) {
                const int kc = BASE + i;
                bf16x8 a[2];
#pragma unroll
                for (int rt = 0; rt < 2; ++rt)
                    a[rt] = *(const bf16x8*)(slab + ((size_t)(kc * 4 + quad) * 32 + rt * 16 + n) * 8);
#pragma unroll
                for (int rt = 0; rt < 2; ++rt)
#pragma unroll
                    for (int g = 0; g < 3; ++g)
                        acc[rt][g] = MFMA16(a[rt], wf[i][g], acc[rt][g]);
            }
    } else if (s > 0) {                    // h_0 = 0: skip at s==0
        const ushort_t* slab = rdOwn + (size_t)((s - 1) & mask) * SLAB_H;
#pragma unroll
        for (int i = 0; i < 8; ++i)
            if (i < CNT) {
                const int kc = BASE + i;
                bf16x8 a[2];
#pragma unroll
                for (int rt = 0; rt < 2; ++rt)
                    a[rt] = *(const bf16x8*)(slab + ((size_t)(kc * 4 + quad) * 32 + rt * 16 + n) * 8);
#pragma unroll
                for (int rt = 0; rt < 2; ++rt)
#pragma unroll
                    for (int g = 0; g < 3; ++g)
                        acc[rt][g] = MFMA16(a[rt], wf[i][g], acc[rt][g]);
            }
    }

    // ---- 3. stage K-partials into this phase's LDS buffer
#pragma unroll
    for (int rt = 0; rt < 2; ++rt)
#pragma unroll
        for (int g = 0; g < 3; ++g)
            ldsPh[((w * 2 + rt) * 3 + g) * 64 + lane] = acc[rt][g];

    // barrier: drains PREV phase's stores (per-thread vmcnt) + LDS ready.
    __syncthreads();

    // ---- 4. deferred flag publish for the PREVIOUS phase (stores now acked)
    if (pubPtr && tid == 0)
        __hip_atomic_store(pubPtr, pubVal, __ATOMIC_RELAXED, __HIP_MEMORY_SCOPE_AGENT);

    // ---- 5. reduce (8 wp partials) + gate one row per thread
    const float* ldsF = (const float*)ldsPh;
    float sz = 0.f, sr = 0.f, sxh = 0.f, srh = 0.f;
#pragma unroll
    for (int wp = 0; wp < 8; ++wp) {
        const bool xw = (XKC == 8) ? (wp == 0) : (wp < 4);
        const int tb = (wp * 2 + rt_src) * 3;
        const float vz = ldsF[(size_t)((tb + 0) * 64 + quad_src * 16 + n) * 4 + reg];
        const float vr = ldsF[(size_t)((tb + 1) * 64 + quad_src * 16 + n) * 4 + reg];
        const float vh = ldsF[(size_t)((tb + 2) * 64 + quad_src * 16 + n) * 4 + reg];
        sz += vz; sr += vr;
        if (xw) sxh += vh; else srh += vh;
    }
    const float z  = sigmf(sz + bzz);
    const float r  = sigmf(sr + brr);
    const float hh = tanhfast(sxh + bxh + r * (srh + brh));
    const float hn = z * hc + (1.f - z) * hh;
    hc = hn;

    // ---- 6. publish h (fire-and-forget; drained at next phase's barrier)
    {
        ushort_t* sw = wrOwn + (size_t)(s & mask) * SLAB_H;
        const float v2 = __shfl_xor(hn, 1);
        if ((lane & 1) == 0) {
            const unsigned pk = (unsigned)f2bf(hn) | ((unsigned)f2bf(v2) << 16);
            const size_t e = ((size_t)(u_ >> 3) * 32 + r_local) * 8 + (u_ & 7);
            __hip_atomic_store((unsigned*)sw + (e >> 1), pk,
                               __ATOMIC_RELAXED, __HIP_MEMORY_SCOPE_AGENT);
        }
    }
}

// ---------------------------------------------------------------------------
// gru_run: one GRU layer, 64 WGs x 512 thr (8 waves), 512 steps x 2 phases.
// Wave K-roles (same as R6):
//   XKC=8  (L0): w0 = x (embBN gather, 8 kc); w1..w7 = h {5,5,5,5,4,4,4} kc
//   XKC=32 (L1/2): w0..w3 = x (prev slab, 8 kc each); w4..w7 = h (8 kc each)
// ---------------------------------------------------------------------------
template<int XKC, bool EMB>
__device__ __forceinline__ void gru_run(
    const int* __restrict__ tokens, const ushort_t* __restrict__ embBN,
    const ushort_t* __restrict__ WkT, const ushort_t* __restrict__ WrT,
    const float* __restrict__ gb,
    ushort_t* __restrict__ hxA, ushort_t* __restrict__ hxB,
    const ushort_t* __restrict__ hxPA, const ushort_t* __restrict__ hxPB,
    float* __restrict__ Hf, unsigned* __restrict__ flags,
    const int layer, const int lwg, const int RING,
    f32x4* __restrict__ ldsRed)
{
    const int tid  = threadIdx.x;
    const int lane = tid & 63;
    const int w    = tid >> 6;             // 0..7
    const int n    = lane & 15, quad = lane >> 4;
    const int u_   = lwg * 16 + n;
    const int mask = RING - 1;

    bool ISX; int CNT, BASE;
    if (XKC == 8) {
        ISX = (w == 0);
        if (w == 0)      { CNT = 8; BASE = 0; }
        else if (w <= 4) { CNT = 5; BASE = (w - 1) * 5; }
        else             { CNT = 4; BASE = 20 + (w - 5) * 4; }
    } else {
        ISX = (w < 4);
        CNT = 8; BASE = (w & 3) * 8;
    }
    const int KROW = ISX ? (EMB ? 256 : 1024) : 1024;
    const ushort_t* WT = ISX ? WkT : WrT;

    // ---- preload weight B-fragments to registers (static-indexed) ----
    bf16x8 wf[8][3];
#pragma unroll
    for (int i = 0; i < 8; ++i)
        if (i < CNT) {
            const int kc = BASE + i;
#pragma unroll
            for (int g = 0; g < 3; ++g)
                wf[i][g] = *(const bf16x8*)(WT + (size_t)(g * 1024 + u_) * KROW
                                            + kc * 32 + quad * 8);
        }

    const float bzz = gb[u_]        + gb[3072 + u_];
    const float brr = gb[1024 + u_] + gb[4096 + u_];
    const float bxh = gb[2048 + u_];
    const float brh = gb[5120 + u_];

    // per-thread gating row (within half): r_local = w*4 + quad
    const int r_local  = w * 4 + quad;
    const int rt_src   = r_local >> 4;
    const int quad_src = (r_local >> 2) & 3;
    const int reg      = r_local & 3;
    float hc0 = 0.f, hc1 = 0.f;

    const unsigned* fPA = (EMB) ? nullptr : flags + ((layer - 1) * 2 + 0) * 64;
    const unsigned* fPB = (EMB) ? nullptr : flags + ((layer - 1) * 2 + 1) * 64;
    const unsigned* fOA = flags + (layer * 2 + 0) * 64;
    const unsigned* fOB = flags + (layer * 2 + 1) * 64;
    unsigned* pubA = flags + (layer * 2 + 0) * 64 + lwg;
    unsigned* pubB = flags + (layer * 2 + 1) * 64 + lwg;
    const unsigned* bpBase = (layer < 2) ? flags + ((layer + 1) * 2 + 0) * 64 : nullptr;

    for (int s = 0; s < 512; ++s) {
        // epoch fence: drop stale L2 copies of ring addresses on wrap
        if (s == 256) __threadfence();

        const bool bpNow = bpBase && ((s & 15) == 0) && (s + 16 > RING);

        // Phase A (rows 0..31). Publishes flagB = s (ack of B(s-1)).
        gru_phase<XKC, EMB>(s, tid, lane, w, n, quad, ISX, CNT, BASE,
            0, mask, tokens, embBN, hxPA, hxA, hxA,
            fPA, (s > 0) ? fOA : nullptr,
            (s > 0) ? pubB : nullptr, (unsigned)s,
            bpNow ? bpBase : nullptr, (unsigned)(s + 16 - RING),
            wf, bzz, brr, bxh, brh, rt_src, quad_src, reg, r_local, u_,
            hc0, ldsRed);

        // Phase B (rows 32..63). Publishes flagA = s+1 (ack of A(s)).
        gru_phase<XKC, EMB>(s, tid, lane, w, n, quad, ISX, CNT, BASE,
            32, mask, tokens, embBN, hxPB, hxB, hxB,
            fPB, (s > 0) ? fOB : nullptr,
            pubA, (unsigned)(s + 1),
            nullptr, 0u,
            wf, bzz, brr, bxh, brh, rt_src, quad_src, reg, r_local, u_,
            hc1, ldsRed + 3072);
    }

    // drain B(511) stores, then final flagB = 512 (closes last-step deps)
    __syncthreads();
    if (tid == 0)
        __hip_atomic_store(pubB, 512u, __ATOMIC_RELAXED, __HIP_MEMORY_SCOPE_AGENT);

    if (Hf != nullptr) {
        Hf[(size_t)r_local * 1024 + u_]        = hc0;
        Hf[(size_t)(32 + r_local) * 1024 + u_] = hc1;
    }
}

// ---------------------------------------------------------------------------
// fused 3-layer pipelined GRU. grid = 256 WGs x 512 thr; XCD slot mapping is
// a PERF HINT only (correctness is placement-independent):
// slots {0,1}->L0, {2,3}->L1, {4,5}->L2, {6,7} exit. lwg = rep*2+(slot&1).
// ---------------------------------------------------------------------------
__global__ __launch_bounds__(512, 2) void gru_fused(
    const int* __restrict__ tokens, const ushort_t* __restrict__ embBN,
    const ushort_t* __restrict__ WkT0, const ushort_t* __restrict__ WkT1,
    const ushort_t* __restrict__ WkT2,
    const ushort_t* __restrict__ WrT0, const ushort_t* __restrict__ WrT1,
    const ushort_t* __restrict__ WrT2,
    const float* __restrict__ gb0, const float* __restrict__ gb1,
    const float* __restrict__ gb2,
    ushort_t* __restrict__ Hx, float* __restrict__ Hf,
    unsigned* __restrict__ flags, int RING)
{
    __shared__ f32x4 ldsRed[6144];            // 96 KB: 2 phases x 48 x 64
    const int slot = blockIdx.x & 7;
    const int rep  = blockIdx.x >> 3;         // 0..31
    const int layer = slot >> 1;
    if (layer >= 3) return;                   // slots 6,7: idle
    const int lwg = rep * 2 + (slot & 1);     // 0..63

    // once per dispatch: drop stale/poisoned L2 lines from prior launches
    __threadfence();

    // ring layout: Hx[layer][half][RING][SLAB_H]
    ushort_t* hxA = Hx + (size_t)(layer * 2 + 0) * RING * SLAB_H;
    ushort_t* hxB = Hx + (size_t)(layer * 2 + 1) * RING * SLAB_H;
    const ushort_t* hxPA = (layer > 0) ? Hx + (size_t)((layer - 1) * 2 + 0) * RING * SLAB_H : nullptr;
    const ushort_t* hxPB = (layer > 0) ? Hx + (size_t)((layer - 1) * 2 + 1) * RING * SLAB_H : nullptr;

    if (layer == 0)
        gru_run<8,  true >(tokens, embBN, WkT0, WrT0, gb0, hxA, hxB, nullptr, nullptr,
                           nullptr, flags, 0, lwg, RING, ldsRed);
    else if (layer == 1)
        gru_run<32, false>(nullptr, nullptr, WkT1, WrT1, gb1, hxA, hxB, hxPA, hxPB,
                           nullptr, flags, 1, lwg, RING, ldsRed);
    else
        gru_run<32, false>(nullptr, nullptr, WkT2, WrT2, gb2, hxA, hxB, hxPA, hxPB,
                           Hf, flags, 2, lwg, RING, ldsRed);
}

// ---------------------------------------------------------------------------
// dense + softmax (verified). One WG per (b,f).
// ---------------------------------------------------------------------------
__global__ __launch_bounds__(256, 1) void dense_softmax(
    const float* __restrict__ hfinal, const float* __restrict__ Wd,
    const float* __restrict__ bd, float* __restrict__ out)
{
    const int tid = threadIdx.x;
    const int bf = blockIdx.x;
    __shared__ float sv[256];
    __shared__ float red[256];
    sv[tid] = hfinal[bf * 256 + tid];
    __syncthreads();
    float a0 = bd[tid], a1 = bd[tid + 256];
    for (int d = 0; d < 256; ++d) {
        float s = sv[d];
        a0 = fmaf(s, Wd[d * 512 + tid], a0);
        a1 = fmaf(s, Wd[d * 512 + tid + 256], a1);
    }
    red[tid] = fmaxf(a0, a1);
    __syncthreads();
    for (int st = 128; st > 0; st >>= 1) {
        if (tid < st) red[tid] = fmaxf(red[tid], red[tid + st]);
        __syncthreads();
    }
    const float mx = red[0];
    __syncthreads();
    float e0 = __expf(a0 - mx), e1 = __expf(a1 - mx);
    red[tid] = e0 + e1;
    __syncthreads();
    for (int st = 128; st > 0; st >>= 1) {
        if (tid < st) red[tid] += red[tid + st];
        __syncthreads();
    }
    const float inv = 1.f / red[0];
    out[(size_t)bf * 512 + tid] = e0 * inv;
    out[(size_t)bf * 512 + tid + 256] = e1 * inv;
}

// ---------------------------------------------------------------------------
extern "C" void kernel_launch(void* const* d_in, const int* in_sizes, int n_in,
                              void* d_out, int out_size, void* d_ws, size_t ws_size,
                              hipStream_t stream)
{
    (void)in_sizes; (void)n_in; (void)out_size;

    const int*   tokens = (const int*)d_in[0];
    const float* emb    = (const float*)d_in[1];
    const float* gamma  = (const float*)d_in[2];
    const float* beta   = (const float*)d_in[3];
    const float* mean   = (const float*)d_in[4];
    const float* var    = (const float*)d_in[5];
    const float* gk[3]  = {(const float*)d_in[6], (const float*)d_in[9],  (const float*)d_in[12]};
    const float* gr[3]  = {(const float*)d_in[7], (const float*)d_in[10], (const float*)d_in[13]};
    const float* gbb[3] = {(const float*)d_in[8], (const float*)d_in[11], (const float*)d_in[14]};
    const float* dw  = (const float*)d_in[15];
    const float* db  = (const float*)d_in[16];

    // workspace carve: fixed ~33.6 MB, Hx rings take the rest
    char* p = (char*)d_ws;
    ushort_t* WkT0  = (ushort_t*)p; p += (size_t)3072 * 256 * 2;
    ushort_t* WkT1  = (ushort_t*)p; p += (size_t)3072 * 1024 * 2;
    ushort_t* WkT2  = (ushort_t*)p; p += (size_t)3072 * 1024 * 2;
    ushort_t* WrTb[3];
    for (int l = 0; l < 3; ++l) { WrTb[l] = (ushort_t*)p; p += (size_t)3072 * 1024 * 2; }
    ushort_t* embBN = (ushort_t*)p; p += (size_t)512 * 256 * 2;
    float*    Hf    = (float*)p;    p += (size_t)64 * 1024 * 4;
    unsigned* flags = (unsigned*)p; p += 4096;
    ushort_t* Hx    = (ushort_t*)p;
    const size_t rem = ws_size - (size_t)(p - (char*)d_ws);
    // RING=512: no address reuse. Else RING=256 + threadfence at s==256.
    const int RING = (rem >= (size_t)6 * 512 * SLAB_H * 2) ? 512 : 256;

    // MUST zero every launch: 0xAA ws poison would satisfy every flag poll.
    hipMemsetAsync(flags, 0, 4096, stream);

    pack_w<<<dim3(4, 48),  256, 0, stream>>>(gk[0], WkT0, 256);
    pack_w<<<dim3(16, 48), 256, 0, stream>>>(gk[1], WkT1, 1024);
    pack_w<<<dim3(16, 48), 256, 0, stream>>>(gk[2], WkT2, 1024);
    for (int l = 0; l < 3; ++l)
        pack_w<<<dim3(16, 48), 256, 0, stream>>>(gr[l], WrTb[l], 1024);

    embed_bn<<<512, 256, 0, stream>>>(emb, gamma, beta, mean, var, embBN);

    gru_fused<<<256, 512, 0, stream>>>(
        tokens, embBN, WkT0, WkT1, WkT2,
        WrTb[0], WrTb[1], WrTb[2], gbb[0], gbb[1], gbb[2],
        Hx, Hf, flags, RING);

    dense_softmax<<<256, 256, 0, stream>>>(Hf, dw, db, (float*)d_out);
}